// Round 1
// 625.256 us; speedup vs baseline: 1.0705x; 1.0705x over previous
//
#include <hip/hip_runtime.h>

// Problem constants (match reference)
#define NN 500000          // nodes
#define FF 128             // feature dim
#define EE 4000000         // edges
#define BB 4               // graphs
#define GG 32              // voxels per dim
#define VV (BB * GG * GG * GG)   // 131072 voxel slots

// d_out layout (flat float32, reference return order)
#define OUT_X    0
#define OUT_POS  (VV * FF)                 // 16,777,216
#define OUT_EIDX (OUT_POS + VV * 3)        // 17,170,432
#define OUT_ATTR (OUT_EIDX + 2 * EE)       // 25,170,432
#define OUT_MASK (OUT_ATTR + 3 * EE)       // 37,170,432

// ---------------------------------------------------------------------------
// Per-node: voxel id, histogram, pos sums. 2.5M atomics on a 2 MB L2-resident
// region — cheap.
// ---------------------------------------------------------------------------
__global__ __launch_bounds__(256) void vid_kernel(
    const float* __restrict__ pos, const int* __restrict__ batch,
    int* __restrict__ vid, unsigned int* __restrict__ cnt,
    float* __restrict__ pos_sum)
{
    int n = blockIdx.x * 256 + threadIdx.x;
    if (n >= NN) return;
    float px = pos[3 * n + 0], py = pos[3 * n + 1], pz = pos[3 * n + 2];
    int vx = min(max((int)floorf(px * 0.125f), 0), GG - 1);
    int vy = min(max((int)floorf(py * 0.125f), 0), GG - 1);
    int vz = min(max((int)floorf(pz * 0.125f), 0), GG - 1);
    int v = batch[n] * (GG * GG * GG) + vx * (GG * GG) + vy * GG + vz;
    vid[n] = v;
    atomicAdd(&cnt[v], 1u);
    atomicAdd(&pos_sum[3 * v + 0], px);
    atomicAdd(&pos_sum[3 * v + 1], py);
    atomicAdd(&pos_sum[3 * v + 2], pz);
}

// ---------------------------------------------------------------------------
// 3-pass exclusive scan over cnt[VV] -> offs[VV].
// ---------------------------------------------------------------------------
__global__ __launch_bounds__(256) void scan_local_kernel(
    const unsigned int* __restrict__ cnt, unsigned int* __restrict__ offs,
    unsigned int* __restrict__ bsum)
{
    __shared__ unsigned int s[256];
    int i = blockIdx.x * 256 + threadIdx.x;
    unsigned int val = cnt[i];
    s[threadIdx.x] = val;
    __syncthreads();
    for (int d = 1; d < 256; d <<= 1) {
        unsigned int t = (threadIdx.x >= d) ? s[threadIdx.x - d] : 0u;
        __syncthreads();
        s[threadIdx.x] += t;
        __syncthreads();
    }
    offs[i] = s[threadIdx.x] - val;              // exclusive
    if (threadIdx.x == 255) bsum[blockIdx.x] = s[255];
}

__global__ __launch_bounds__(512) void scan_bsum_kernel(unsigned int* __restrict__ bsum)
{
    __shared__ unsigned int s[512];
    unsigned int val = bsum[threadIdx.x];
    s[threadIdx.x] = val;
    __syncthreads();
    for (int d = 1; d < 512; d <<= 1) {
        unsigned int t = (threadIdx.x >= d) ? s[threadIdx.x - d] : 0u;
        __syncthreads();
        s[threadIdx.x] += t;
        __syncthreads();
    }
    bsum[threadIdx.x] = s[threadIdx.x] - val;    // exclusive
}

__global__ __launch_bounds__(256) void scan_add_kernel(
    unsigned int* __restrict__ offs, const unsigned int* __restrict__ bsum,
    unsigned int* __restrict__ cursor)
{
    int i = blockIdx.x * 256 + threadIdx.x;
    unsigned int o = offs[i] + bsum[blockIdx.x];
    offs[i] = o;
    cursor[i] = o;
}

// ---------------------------------------------------------------------------
// Scatter node ids into CSR order (counting sort placement).
// ---------------------------------------------------------------------------
__global__ __launch_bounds__(256) void scatter_kernel(
    const int* __restrict__ vid, unsigned int* __restrict__ cursor,
    unsigned int* __restrict__ order)
{
    int n = blockIdx.x * 256 + threadIdx.x;
    if (n >= NN) return;
    unsigned int p = atomicAdd(&cursor[vid[n]], 1u);
    order[p] = n;
}

// ---------------------------------------------------------------------------
// One wave per voxel, latency-optimized:
//  - all node indices for the voxel loaded with ONE coalesced lane-parallel
//    load, then broadcast via __shfl (kills the per-node order[] dependent
//    load in the old version's chain: order -> x-row -> fmax, ~1100cy/node).
//  - wave split in half: lanes 0-31 reduce even nodes, lanes 32-63 odd nodes,
//    each lane loads float4 (16 B/lane) so one VMEM instruction covers TWO
//    rows; 2-deep unroll => 4 rows in flight per wave (old version: 1).
//  - halves merged with __shfl_xor(32) at the end.
// Writes every voxel exactly once (0 for empty) — no memset, no atomics.
// ---------------------------------------------------------------------------
__global__ __launch_bounds__(256) void pool_kernel(
    const float* __restrict__ x, const unsigned int* __restrict__ order,
    const unsigned int* __restrict__ offs, const unsigned int* __restrict__ cnt,
    float* __restrict__ out_x)
{
    int w = threadIdx.x >> 6;          // wave index in block
    int lane = threadIdx.x & 63;
    int half = lane >> 5;              // 0: even-index nodes, 1: odd-index nodes
    int fl = lane & 31;                // float4 chunk within the 128-f row
    int v = blockIdx.x * 4 + w;
    unsigned int start = offs[v];
    unsigned int c = cnt[v];

    float4 m0 = make_float4(-INFINITY, -INFINITY, -INFINITY, -INFINITY);
    float4 m1 = m0;

    for (unsigned int base = 0; base < c; base += 64) {
        unsigned int rem = min(c - base, 64u);
        // lane i caches order[start+base+i]; one coalesced load per 64 nodes
        unsigned int idx = (lane < rem) ? order[start + base + lane] : 0u;
        unsigned int k = (unsigned int)half;       // this half's first node
        for (; k + 2 < rem; k += 4) {              // 2 nodes per half, 4 rows in flight
            unsigned int n0 = __shfl(idx, (int)k);
            unsigned int n1 = __shfl(idx, (int)(k + 2));
            float4 a = ((const float4*)(x + (size_t)n0 * FF))[fl];
            float4 b = ((const float4*)(x + (size_t)n1 * FF))[fl];
            m0.x = fmaxf(m0.x, a.x); m0.y = fmaxf(m0.y, a.y);
            m0.z = fmaxf(m0.z, a.z); m0.w = fmaxf(m0.w, a.w);
            m1.x = fmaxf(m1.x, b.x); m1.y = fmaxf(m1.y, b.y);
            m1.z = fmaxf(m1.z, b.z); m1.w = fmaxf(m1.w, b.w);
        }
        if (k < rem) {                             // tail node for this half
            unsigned int n0 = __shfl(idx, (int)k);
            float4 a = ((const float4*)(x + (size_t)n0 * FF))[fl];
            m0.x = fmaxf(m0.x, a.x); m0.y = fmaxf(m0.y, a.y);
            m0.z = fmaxf(m0.z, a.z); m0.w = fmaxf(m0.w, a.w);
        }
    }

    // merge the two accumulators, then the two wave halves
    float4 m;
    m.x = fmaxf(m0.x, m1.x); m.y = fmaxf(m0.y, m1.y);
    m.z = fmaxf(m0.z, m1.z); m.w = fmaxf(m0.w, m1.w);
    m.x = fmaxf(m.x, __shfl_xor(m.x, 32));
    m.y = fmaxf(m.y, __shfl_xor(m.y, 32));
    m.z = fmaxf(m.z, __shfl_xor(m.z, 32));
    m.w = fmaxf(m.w, __shfl_xor(m.w, 32));

    if (c == 0) m = make_float4(0.0f, 0.0f, 0.0f, 0.0f);
    if (half == 0)
        ((float4*)(out_x + (size_t)v * FF))[fl] = m;
}

// ---------------------------------------------------------------------------
// pooled_pos = pos_sum / max(count, 1).
// ---------------------------------------------------------------------------
__global__ __launch_bounds__(256) void fix_pos_kernel(
    float* __restrict__ out_pos, const float* __restrict__ pos_sum,
    const unsigned int* __restrict__ cnt)
{
    int v = blockIdx.x * 256 + threadIdx.x;
    float inv = 1.0f / fmaxf((float)cnt[v], 1.0f);
    out_pos[3 * v + 0] = pos_sum[3 * v + 0] * inv;
    out_pos[3 * v + 1] = pos_sum[3 * v + 1] * inv;
    out_pos[3 * v + 2] = pos_sum[3 * v + 2] * inv;
}

// ---------------------------------------------------------------------------
// Per-edge: remap endpoints, self-loop mask, Cartesian attr.
// ---------------------------------------------------------------------------
__global__ __launch_bounds__(256) void edge_kernel(
    const int* __restrict__ eidx, const int* __restrict__ vid,
    const float* __restrict__ pooled_pos, float* __restrict__ out)
{
    int e = blockIdx.x * 256 + threadIdx.x;
    if (e >= EE) return;
    int sv = vid[eidx[e]];
    int dv = vid[eidx[EE + e]];
    bool m = (sv != dv);
    out[OUT_EIDX + e] = (float)sv;
    out[OUT_EIDX + EE + e] = (float)dv;
    float ax = 0.0f, ay = 0.0f, az = 0.0f;
    if (m) {
        ax = (pooled_pos[3 * dv + 0] - pooled_pos[3 * sv + 0]) * 0.0625f + 0.5f;
        ay = (pooled_pos[3 * dv + 1] - pooled_pos[3 * sv + 1]) * 0.0625f + 0.5f;
        az = (pooled_pos[3 * dv + 2] - pooled_pos[3 * sv + 2]) * 0.0625f + 0.5f;
    }
    out[OUT_ATTR + 3 * e + 0] = ax;
    out[OUT_ATTR + 3 * e + 1] = ay;
    out[OUT_ATTR + 3 * e + 2] = az;
    out[OUT_MASK + e] = m ? 1.0f : 0.0f;
}

extern "C" void kernel_launch(void* const* d_in, const int* in_sizes, int n_in,
                              void* d_out, int out_size, void* d_ws, size_t ws_size,
                              hipStream_t stream)
{
    const float* x     = (const float*)d_in[0];
    const float* pos   = (const float*)d_in[1];
    const int*   batch = (const int*)d_in[2];
    const int*   eidx  = (const int*)d_in[3];
    float* out = (float*)d_out;

    // workspace layout (bytes):
    char* ws = (char*)d_ws;
    unsigned int* cnt     = (unsigned int*)(ws + 0);               // VV*4   = 524288
    float*        pos_sum = (float*)(ws + 524288);                 // VV*12  -> 2097152
    int*          vid     = (int*)(ws + 2097152);                  // NN*4   -> 4097152
    unsigned int* offs    = (unsigned int*)(ws + 4097152);         // VV*4   -> 4621440
    unsigned int* cursor  = (unsigned int*)(ws + 4621440);         // VV*4   -> 5145728
    unsigned int* bsum    = (unsigned int*)(ws + 5145728);         // 512*4  -> 5147776
    unsigned int* order   = (unsigned int*)(ws + 5147776);         // NN*4   -> 7147776

    // zero cnt + pos_sum only (2 MB)
    hipMemsetAsync(d_ws, 0, 2097152, stream);

    vid_kernel<<<(NN + 255) / 256, 256, 0, stream>>>(pos, batch, vid, cnt, pos_sum);
    scan_local_kernel<<<VV / 256, 256, 0, stream>>>(cnt, offs, bsum);
    scan_bsum_kernel<<<1, 512, 0, stream>>>(bsum);
    scan_add_kernel<<<VV / 256, 256, 0, stream>>>(offs, bsum, cursor);
    scatter_kernel<<<(NN + 255) / 256, 256, 0, stream>>>(vid, cursor, order);
    pool_kernel<<<VV / 4, 256, 0, stream>>>(x, order, offs, cnt, out + OUT_X);
    fix_pos_kernel<<<VV / 256, 256, 0, stream>>>(out + OUT_POS, pos_sum, cnt);
    edge_kernel<<<(EE + 255) / 256, 256, 0, stream>>>(eidx, vid, out + OUT_POS, out);
}

// Round 2
// 554.370 us; speedup vs baseline: 1.2074x; 1.1279x over previous
//
#include <hip/hip_runtime.h>

// Problem constants (match reference)
#define NN 500000          // nodes
#define FF 128             // feature dim
#define EE 4000000         // edges
#define BB 4               // graphs
#define GG 32              // voxels per dim
#define VV (BB * GG * GG * GG)   // 131072 voxel slots

// d_out layout (flat float32, reference return order)
#define OUT_X    0
#define OUT_POS  (VV * FF)                 // 16,777,216
#define OUT_EIDX (OUT_POS + VV * 3)        // 17,170,432
#define OUT_ATTR (OUT_EIDX + 2 * EE)       // 25,170,432
#define OUT_MASK (OUT_ATTR + 3 * EE)       // 37,170,432

// ---------------------------------------------------------------------------
// Per-node: voxel id + histogram. Only ONE fabric atomic per node now
// (pos sums moved into pool_kernel's CSR walk).
// ---------------------------------------------------------------------------
__global__ __launch_bounds__(256) void vid_kernel(
    const float* __restrict__ pos, const int* __restrict__ batch,
    int* __restrict__ vid, unsigned int* __restrict__ cnt)
{
    int n = blockIdx.x * 256 + threadIdx.x;
    if (n >= NN) return;
    float px = pos[3 * n + 0], py = pos[3 * n + 1], pz = pos[3 * n + 2];
    int vx = min(max((int)floorf(px * 0.125f), 0), GG - 1);
    int vy = min(max((int)floorf(py * 0.125f), 0), GG - 1);
    int vz = min(max((int)floorf(pz * 0.125f), 0), GG - 1);
    int v = batch[n] * (GG * GG * GG) + vx * (GG * GG) + vy * GG + vz;
    vid[n] = v;
    atomicAdd(&cnt[v], 1u);
}

// ---------------------------------------------------------------------------
// 3-pass exclusive scan over cnt[VV] -> offs[VV].
// ---------------------------------------------------------------------------
__global__ __launch_bounds__(256) void scan_local_kernel(
    const unsigned int* __restrict__ cnt, unsigned int* __restrict__ offs,
    unsigned int* __restrict__ bsum)
{
    __shared__ unsigned int s[256];
    int i = blockIdx.x * 256 + threadIdx.x;
    unsigned int val = cnt[i];
    s[threadIdx.x] = val;
    __syncthreads();
    for (int d = 1; d < 256; d <<= 1) {
        unsigned int t = (threadIdx.x >= d) ? s[threadIdx.x - d] : 0u;
        __syncthreads();
        s[threadIdx.x] += t;
        __syncthreads();
    }
    offs[i] = s[threadIdx.x] - val;              // exclusive
    if (threadIdx.x == 255) bsum[blockIdx.x] = s[255];
}

__global__ __launch_bounds__(512) void scan_bsum_kernel(unsigned int* __restrict__ bsum)
{
    __shared__ unsigned int s[512];
    unsigned int val = bsum[threadIdx.x];
    s[threadIdx.x] = val;
    __syncthreads();
    for (int d = 1; d < 512; d <<= 1) {
        unsigned int t = (threadIdx.x >= d) ? s[threadIdx.x - d] : 0u;
        __syncthreads();
        s[threadIdx.x] += t;
        __syncthreads();
    }
    bsum[threadIdx.x] = s[threadIdx.x] - val;    // exclusive
}

__global__ __launch_bounds__(256) void scan_add_kernel(
    unsigned int* __restrict__ offs, const unsigned int* __restrict__ bsum,
    unsigned int* __restrict__ cursor)
{
    int i = blockIdx.x * 256 + threadIdx.x;
    unsigned int o = offs[i] + bsum[blockIdx.x];
    offs[i] = o;
    cursor[i] = o;
}

// ---------------------------------------------------------------------------
// Scatter node ids into CSR order (counting sort placement).
// ---------------------------------------------------------------------------
__global__ __launch_bounds__(256) void scatter_kernel(
    const int* __restrict__ vid, unsigned int* __restrict__ cursor,
    unsigned int* __restrict__ order)
{
    int n = blockIdx.x * 256 + threadIdx.x;
    if (n >= NN) return;
    unsigned int p = atomicAdd(&cursor[vid[n]], 1u);
    order[p] = n;
}

// ---------------------------------------------------------------------------
// One wave per voxel, quarter-split for max memory-level parallelism:
//  - node indices for the voxel loaded with ONE coalesced lane-parallel load,
//    broadcast via per-lane-index __shfl.
//  - 4 groups of 16 lanes; group g reduces nodes k ≡ g (mod 4). Each group
//    covers a FULL 128-f row as two independent float4 loads ([fl], [fl+16]).
//    One loop iteration = 4 different rows in flight from 2 VMEM instrs
//    (2 KB/wave in flight); iterations/voxel = ceil(c/4).
//  - groups merged with __shfl_xor(16) + __shfl_xor(32).
//  - pos sums fused here (gather pos[idx] per active lane, butterfly reduce,
//    lane 0 writes pooled_pos) — replaces 1.5M fabric atomics + fix_pos pass.
// Writes every voxel exactly once (0 for empty) — no memset, no atomics.
// ---------------------------------------------------------------------------
__global__ __launch_bounds__(256) void pool_kernel(
    const float* __restrict__ x, const float* __restrict__ pos,
    const unsigned int* __restrict__ order,
    const unsigned int* __restrict__ offs, const unsigned int* __restrict__ cnt,
    float* __restrict__ out_x, float* __restrict__ out_pos)
{
    int w = threadIdx.x >> 6;          // wave index in block
    int lane = threadIdx.x & 63;
    int g = lane >> 4;                 // group 0..3 (node subset k ≡ g mod 4)
    int fl = lane & 15;                // float4 chunk within group's row halves
    int v = blockIdx.x * 4 + w;
    unsigned int start = offs[v];
    unsigned int c = cnt[v];

    float4 mlo = make_float4(-INFINITY, -INFINITY, -INFINITY, -INFINITY);
    float4 mhi = mlo;
    float sx = 0.0f, sy = 0.0f, sz = 0.0f;

    for (unsigned int base = 0; base < c; base += 64) {
        unsigned int rem = min(c - base, 64u);
        // lane i caches order[start+base+i]; one coalesced load per 64 nodes
        unsigned int idx = (lane < rem) ? order[start + base + lane] : 0u;
        // pos accumulation (independent of row loads; latency overlaps)
        if (lane < rem) {
            const float* pp = pos + 3 * (size_t)idx;
            sx += pp[0]; sy += pp[1]; sz += pp[2];
        }
        for (unsigned int k = (unsigned int)g; k < rem; k += 4) {
            unsigned int n = __shfl(idx, (int)k);
            const float4* row = (const float4*)(x + (size_t)n * FF);
            float4 a = row[fl];
            float4 b = row[fl + 16];
            mlo.x = fmaxf(mlo.x, a.x); mlo.y = fmaxf(mlo.y, a.y);
            mlo.z = fmaxf(mlo.z, a.z); mlo.w = fmaxf(mlo.w, a.w);
            mhi.x = fmaxf(mhi.x, b.x); mhi.y = fmaxf(mhi.y, b.y);
            mhi.z = fmaxf(mhi.z, b.z); mhi.w = fmaxf(mhi.w, b.w);
        }
    }

    // merge the 4 groups (lanes l, l^16, l^32, l^48 share the same fl)
    #define MERGE(f) f = fmaxf(f, __shfl_xor(f, 16)); f = fmaxf(f, __shfl_xor(f, 32));
    MERGE(mlo.x) MERGE(mlo.y) MERGE(mlo.z) MERGE(mlo.w)
    MERGE(mhi.x) MERGE(mhi.y) MERGE(mhi.z) MERGE(mhi.w)
    #undef MERGE

    // feature write: lanes 0-15 -> chunks 0-15 (mlo), lanes 16-31 -> 16-31 (mhi)
    float4 res = (lane < 16) ? mlo : mhi;
    if (c == 0) res = make_float4(0.0f, 0.0f, 0.0f, 0.0f);
    if (lane < 32)
        ((float4*)(out_x + (size_t)v * FF))[lane] = res;

    // pos butterfly reduce across all 64 lanes, lane 0 writes mean
    for (int d = 1; d < 64; d <<= 1) {
        sx += __shfl_xor(sx, d);
        sy += __shfl_xor(sy, d);
        sz += __shfl_xor(sz, d);
    }
    if (lane == 0) {
        float inv = 1.0f / fmaxf((float)c, 1.0f);
        out_pos[3 * v + 0] = sx * inv;
        out_pos[3 * v + 1] = sy * inv;
        out_pos[3 * v + 2] = sz * inv;
    }
}

// ---------------------------------------------------------------------------
// Per-edge: remap endpoints, self-loop mask, Cartesian attr.
// attr staged through LDS so the 48 MB attr stream is written coalesced
// (direct stride-3 scalar stores span 768 B/instr with ~1/3 useful bytes).
// ---------------------------------------------------------------------------
__global__ __launch_bounds__(256) void edge_kernel(
    const int* __restrict__ eidx, const int* __restrict__ vid,
    const float* __restrict__ pooled_pos, float* __restrict__ out)
{
    __shared__ float sattr[768];
    int e0 = blockIdx.x * 256;
    int e = e0 + threadIdx.x;
    int sv = vid[eidx[e]];
    int dv = vid[eidx[EE + e]];
    bool m = (sv != dv);
    out[OUT_EIDX + e] = (float)sv;
    out[OUT_EIDX + EE + e] = (float)dv;
    float ax = 0.0f, ay = 0.0f, az = 0.0f;
    if (m) {
        ax = (pooled_pos[3 * dv + 0] - pooled_pos[3 * sv + 0]) * 0.0625f + 0.5f;
        ay = (pooled_pos[3 * dv + 1] - pooled_pos[3 * sv + 1]) * 0.0625f + 0.5f;
        az = (pooled_pos[3 * dv + 2] - pooled_pos[3 * sv + 2]) * 0.0625f + 0.5f;
    }
    // stride-3 LDS writes: 3 coprime with 32 banks -> conflict-free
    sattr[3 * threadIdx.x + 0] = ax;
    sattr[3 * threadIdx.x + 1] = ay;
    sattr[3 * threadIdx.x + 2] = az;
    out[OUT_MASK + e] = m ? 1.0f : 0.0f;
    __syncthreads();
    float* dst = out + OUT_ATTR + (size_t)3 * e0;
    #pragma unroll
    for (int i = 0; i < 3; ++i)
        dst[i * 256 + threadIdx.x] = sattr[i * 256 + threadIdx.x];
}

extern "C" void kernel_launch(void* const* d_in, const int* in_sizes, int n_in,
                              void* d_out, int out_size, void* d_ws, size_t ws_size,
                              hipStream_t stream)
{
    const float* x     = (const float*)d_in[0];
    const float* pos   = (const float*)d_in[1];
    const int*   batch = (const int*)d_in[2];
    const int*   eidx  = (const int*)d_in[3];
    float* out = (float*)d_out;

    // workspace layout (bytes):
    char* ws = (char*)d_ws;
    unsigned int* cnt     = (unsigned int*)(ws + 0);               // VV*4   = 524288
    int*          vid     = (int*)(ws + 524288);                   // NN*4   -> 2524288
    unsigned int* offs    = (unsigned int*)(ws + 2524288);         // VV*4   -> 3048576
    unsigned int* cursor  = (unsigned int*)(ws + 3048576);         // VV*4   -> 3572864
    unsigned int* bsum    = (unsigned int*)(ws + 3572864);         // 512*4  -> 3574912
    unsigned int* order   = (unsigned int*)(ws + 3574912);         // NN*4   -> 5574912

    // zero cnt only (512 KB)
    hipMemsetAsync(d_ws, 0, 524288, stream);

    vid_kernel<<<(NN + 255) / 256, 256, 0, stream>>>(pos, batch, vid, cnt);
    scan_local_kernel<<<VV / 256, 256, 0, stream>>>(cnt, offs, bsum);
    scan_bsum_kernel<<<1, 512, 0, stream>>>(bsum);
    scan_add_kernel<<<VV / 256, 256, 0, stream>>>(offs, bsum, cursor);
    scatter_kernel<<<(NN + 255) / 256, 256, 0, stream>>>(vid, cursor, order);
    pool_kernel<<<VV / 4, 256, 0, stream>>>(x, pos, order, offs, cnt,
                                            out + OUT_X, out + OUT_POS);
    edge_kernel<<<(EE + 255) / 256, 256, 0, stream>>>(eidx, vid, out + OUT_POS, out);
}